// Round 2
// baseline (240.521 us; speedup 1.0000x reference)
//
#include <hip/hip_runtime.h>
#include <hip/hip_bf16.h>
#include <stdint.h>

#define N_HEAD 16
#define HDIM 64
#define C_IN 256
#define D_MODEL 1024          // N_HEAD*HDIM
#define N_SP 64
#define L_SP 256
#define A_L 2
#define MS (N_SP * L_SP)      // 16384 spatial points
#define MA (N_SP * A_L * L_SP)// 32768 aux points
#define ATT_SCALE 0.125f

typedef __attribute__((ext_vector_type(8))) short bf16x8;
typedef __attribute__((ext_vector_type(4))) float f32x4;
typedef __attribute__((ext_vector_type(8))) unsigned short u16x8;
typedef __attribute__((ext_vector_type(4))) unsigned int u32x4;

static __device__ __forceinline__ float bf2f(__hip_bfloat16 v) { return __bfloat162float(v); }
static __device__ __forceinline__ __hip_bfloat16 f2bf(float v) { return __float2bfloat16(v); }
static __device__ __forceinline__ unsigned short bfbits(float v) {
    union { __hip_bfloat16 h; unsigned short u; } cv;
    cv.h = __float2bfloat16(v);
    return cv.u;
}

// ---------------- weight prep: fp32 -> bf16, grouped per head-chunk ----------------
// Wqkv grouped layout: chunk c rows [c*3*HC*64 ..): [q heads c*HC..(c+1)*HC; k same; v same]
// Wakv grouped layout: chunk c rows [c*2*HC*64 ..): [k heads chunk; v heads chunk]
__global__ __launch_bounds__(256) void prep_weights(
    const float* __restrict__ wq, const float* __restrict__ bq,
    const float* __restrict__ wk, const float* __restrict__ bk,
    const float* __restrict__ wv, const float* __restrict__ bv,
    const float* __restrict__ wo,
    __hip_bfloat16* __restrict__ Wqkv, float* __restrict__ BiasQKV,
    __hip_bfloat16* __restrict__ Wakv, float* __restrict__ BiasAKV,
    __hip_bfloat16* __restrict__ Wo, int HC)
{
    int idx = blockIdx.x * 256 + threadIdx.x;   // grid covers 3*1024*256
    {
        int row = idx >> 8, col = idx & 255;
        int CH = 3 * HC * 64;
        int c = row / CH, r = row % CH;
        int p = r / (HC * 64), hh = r % (HC * 64);
        int srow = c * HC * 64 + hh;
        const float* w = (p == 0) ? wq : (p == 1) ? wk : wv;
        Wqkv[idx] = f2bf(w[(size_t)srow * C_IN + col]);
        if (col == 0) {
            const float* b = (p == 0) ? bq : (p == 1) ? bk : bv;
            BiasQKV[row] = b[srow];
        }
    }
    if (idx < 2 * D_MODEL * C_IN) {
        int row = idx >> 8, col = idx & 255;
        int CH = 2 * HC * 64;
        int c = row / CH, r = row % CH;
        int p = r / (HC * 64), hh = r % (HC * 64);
        int srow = c * HC * 64 + hh;
        const float* w = (p == 0) ? wk : wv;
        Wakv[idx] = f2bf(w[(size_t)srow * C_IN + col]);
        if (col == 0) BiasAKV[row] = ((p == 0) ? bk : bv)[srow];
    }
    if (idx < C_IN * D_MODEL) Wo[idx] = f2bf(wo[idx]);
}

// ---------------- [C=256, M] fp32 -> [M, 256] bf16 transpose ----------------
__global__ __launch_bounds__(256) void transpose_c2m(
    const float* __restrict__ src, __hip_bfloat16* __restrict__ dst, int M)
{
    __shared__ float tile[32][33];
    int tx = threadIdx.x, ty = threadIdx.y;
    int m0 = blockIdx.x * 32, c0 = blockIdx.y * 32;
#pragma unroll
    for (int j = 0; j < 32; j += 8)
        tile[ty + j][tx] = src[(size_t)(c0 + ty + j) * M + m0 + tx];
    __syncthreads();
#pragma unroll
    for (int j = 0; j < 32; j += 8)
        dst[(size_t)(m0 + ty + j) * C_IN + c0 + tx] = f2bf(tile[tx][ty + j]);
}

// ---------------- bf16 MFMA GEMM: C[M,N] = A[M,K] * B[N,K]^T + bias[M] ----------------
// 128x128 tile, BK=64, 4 waves (2x2), each wave 64x64 via 4x4 mfma_f32_16x16x32_bf16.
template <typename OutT>
__global__ __launch_bounds__(256) void gemm_bt(
    const __hip_bfloat16* __restrict__ A,
    const __hip_bfloat16* __restrict__ B,
    OutT* __restrict__ C,
    const float* __restrict__ bias,
    int M, int N, int K)
{
    __shared__ __align__(16) __hip_bfloat16 As[128 * 64];
    __shared__ __align__(16) __hip_bfloat16 Bs[128 * 64];

    const int tid = threadIdx.x;
    const int lane = tid & 63;
    const int w = tid >> 6;
    const int wr = w >> 1, wc = w & 1;
    const int fr = lane & 15, fq = lane >> 4;
    const int i0 = blockIdx.y * 128, j0 = blockIdx.x * 128;
    const int srow = tid >> 3, sch = (tid & 7) << 3;   // stage row base / col (elems)

    f32x4 acc[4][4];
#pragma unroll
    for (int a = 0; a < 4; ++a)
#pragma unroll
        for (int b = 0; b < 4; ++b) acc[a][b] = (f32x4){0.f, 0.f, 0.f, 0.f};

    for (int k0 = 0; k0 < K; k0 += 64) {
        u32x4 ra[4], rb[4];
#pragma unroll
        for (int is = 0; is < 4; ++is) {
            int row = is * 32 + srow;
            ra[is] = *(const u32x4*)(A + (size_t)(i0 + row) * K + k0 + sch);
            rb[is] = *(const u32x4*)(B + (size_t)(j0 + row) * K + k0 + sch);
        }
#pragma unroll
        for (int is = 0; is < 4; ++is) {
            int row = is * 32 + srow;
            *(u32x4*)(As + row * 64 + sch) = ra[is];
            *(u32x4*)(Bs + row * 64 + sch) = rb[is];
        }
        __syncthreads();
#pragma unroll
        for (int kk = 0; kk < 64; kk += 32) {
            bf16x8 af[4], bb[4];
#pragma unroll
            for (int mi = 0; mi < 4; ++mi)
                af[mi] = *(const bf16x8*)(As + (wr * 64 + mi * 16 + fr) * 64 + kk + fq * 8);
#pragma unroll
            for (int ni = 0; ni < 4; ++ni)
                bb[ni] = *(const bf16x8*)(Bs + (wc * 64 + ni * 16 + fr) * 64 + kk + fq * 8);
#pragma unroll
            for (int mi = 0; mi < 4; ++mi)
#pragma unroll
                for (int ni = 0; ni < 4; ++ni)
                    acc[mi][ni] = __builtin_amdgcn_mfma_f32_16x16x32_bf16(
                        af[mi], bb[ni], acc[mi][ni], 0, 0, 0);
        }
        __syncthreads();
    }

    // epilogue: C/D frag layout col = lane&15, row = (lane>>4)*4 + reg
#pragma unroll
    for (int mi = 0; mi < 4; ++mi) {
#pragma unroll
        for (int r = 0; r < 4; ++r) {
            int row = i0 + wr * 64 + mi * 16 + fq * 4 + r;
            float bv = bias[row];
#pragma unroll
            for (int ni = 0; ni < 4; ++ni) {
                int col = j0 + wc * 64 + ni * 16 + fr;
                float v = acc[mi][ni][r] + bv;
                if constexpr (sizeof(OutT) == 2) C[(size_t)row * N + col] = f2bf(v);
                else                             C[(size_t)row * N + col] = v;
            }
        }
    }
}

// ---------------- windowed attention (W=5: 3 unfold + 2 aux), softmax over W ----------------
// Chunked: qkv has DQ=HC*64 q rows, then DQ k rows, then DQ v rows (each [*, MS]).
// akv has DQ k rows then DQ v rows (each [*, MA]). blockIdx.y = local head.
// NOTE: reference's double-reshape is a flat (3,N)->(N,3) reinterpretation:
//   window w at position n reads source row nn = ((3n+w)&63) + ((3n+w)>>6) - 1 (zero-padded).
__global__ __launch_bounds__(256) void attn_win(
    const __hip_bfloat16* __restrict__ qkv,
    const __hip_bfloat16* __restrict__ akv,
    __hip_bfloat16* __restrict__ ATT,         // [MS, 1024]
    int DQ, int hbase)
{
    const int l = threadIdx.x;
    const int n = blockIdx.x;
    const int h = blockIdx.y;                 // local head in chunk
    const int m = n * L_SP + l;

    int src[3]; float val[3];
#pragma unroll
    for (int wd = 0; wd < 3; ++wd) {
        int f = n * 3 + wd;
        int un = f >> 6;
        int nn = (f & 63) + un - 1;
        bool ok = (nn >= 0) && (nn < N_SP);
        src[wd] = ok ? nn : 0;
        val[wd] = ok ? 1.f : 0.f;
    }

    const __hip_bfloat16* qp  = qkv + (size_t)(h * HDIM) * MS + m;
    const __hip_bfloat16* kb  = qkv + (size_t)(DQ + h * HDIM) * MS + l;
    const __hip_bfloat16* kp0 = kb + src[0] * L_SP;
    const __hip_bfloat16* kp1 = kb + src[1] * L_SP;
    const __hip_bfloat16* kp2 = kb + src[2] * L_SP;
    const __hip_bfloat16* akp = akv + (size_t)(h * HDIM) * MA + n * (A_L * L_SP) + l;

    float s0 = 0.f, s1 = 0.f, s2 = 0.f, s3 = 0.f, s4 = 0.f;
#pragma unroll 4
    for (int dd = 0; dd < HDIM; ++dd) {
        float q = bf2f(qp[(size_t)dd * MS]);
        s0 += q * bf2f(kp0[(size_t)dd * MS]);
        s1 += q * bf2f(kp1[(size_t)dd * MS]);
        s2 += q * bf2f(kp2[(size_t)dd * MS]);
        s3 += q * bf2f(akp[(size_t)dd * MA]);
        s4 += q * bf2f(akp[(size_t)dd * MA + L_SP]);
    }
    s0 *= ATT_SCALE * val[0];   // padded window: k==0 -> score exactly 0 (still in softmax)
    s1 *= ATT_SCALE * val[1];
    s2 *= ATT_SCALE * val[2];
    s3 *= ATT_SCALE;
    s4 *= ATT_SCALE;

    float mx = fmaxf(fmaxf(fmaxf(s0, s1), fmaxf(s2, s3)), s4);
    float e0 = __expf(s0 - mx), e1 = __expf(s1 - mx), e2 = __expf(s2 - mx);
    float e3 = __expf(s3 - mx), e4 = __expf(s4 - mx);
    float inv = 1.f / (e0 + e1 + e2 + e3 + e4);
    float a0 = e0 * inv * val[0];   // padded window: v==0 -> zero contribution
    float a1 = e1 * inv * val[1];
    float a2 = e2 * inv * val[2];
    float a3 = e3 * inv, a4 = e4 * inv;

    const __hip_bfloat16* vb  = qkv + (size_t)(2 * DQ + h * HDIM) * MS + l;
    const __hip_bfloat16* vp0 = vb + src[0] * L_SP;
    const __hip_bfloat16* vp1 = vb + src[1] * L_SP;
    const __hip_bfloat16* vp2 = vb + src[2] * L_SP;
    const __hip_bfloat16* avp = akv + (size_t)(DQ + h * HDIM) * MA + n * (A_L * L_SP) + l;
    __hip_bfloat16* op = ATT + (size_t)m * D_MODEL + (hbase + h) * HDIM;

#pragma unroll
    for (int g = 0; g < 8; ++g) {
        u16x8 pack;
#pragma unroll
        for (int j = 0; j < 8; ++j) {
            int dd = g * 8 + j;
            float acc = a0 * bf2f(vp0[(size_t)dd * MS])
                      + a1 * bf2f(vp1[(size_t)dd * MS])
                      + a2 * bf2f(vp2[(size_t)dd * MS])
                      + a3 * bf2f(avp[(size_t)dd * MA])
                      + a4 * bf2f(avp[(size_t)dd * MA + L_SP]);
            pack[j] = bfbits(acc);
        }
        *(u16x8*)(op + g * 8) = pack;
    }
}

// ---------------- launch ----------------
extern "C" void kernel_launch(void* const* d_in, const int* in_sizes, int n_in,
                              void* d_out, int out_size, void* d_ws, size_t ws_size,
                              hipStream_t stream) {
    const float* x  = (const float*)d_in[0];
    const float* ax = (const float*)d_in[1];
    const float* wq = (const float*)d_in[2];
    const float* bq = (const float*)d_in[3];
    const float* wk = (const float*)d_in[4];
    const float* bk = (const float*)d_in[5];
    const float* wv = (const float*)d_in[6];
    const float* bv = (const float*)d_in[7];
    const float* wo = (const float*)d_in[8];
    const float* bo = (const float*)d_in[9];

    auto pad = [](size_t b) { return (b + 255) & ~(size_t)255; };

    // Fixed-footprint buffers
    const size_t szWqkv  = pad((size_t)3 * D_MODEL * C_IN * 2);
    const size_t szBqkv  = pad((size_t)3 * D_MODEL * 4);
    const size_t szWakv  = pad((size_t)2 * D_MODEL * C_IN * 2);
    const size_t szBakv  = pad((size_t)2 * D_MODEL * 4);
    const size_t szWo    = pad((size_t)C_IN * D_MODEL * 2);
    const size_t szXt    = pad((size_t)MS * C_IN * 2);
    const size_t szAXt   = pad((size_t)MA * C_IN * 2);
    const size_t szATT   = pad((size_t)MS * D_MODEL * 2);
    const size_t fixedB  = szWqkv + szBqkv + szWakv + szBakv + szWo + szXt + szAXt + szATT;

    // Pick the largest head-chunk that fits the workspace.
    int HC = 2;
    {
        const int cand[4] = {16, 8, 4, 2};
        for (int i = 0; i < 4; ++i) {
            int h = cand[i];
            size_t need = fixedB
                        + pad((size_t)3 * h * HDIM * MS * 2)
                        + pad((size_t)2 * h * HDIM * MA * 2)
                        + 65536;
            if (need <= ws_size) { HC = h; break; }
        }
    }
    const int DQ = HC * HDIM;
    const int nchunk = N_HEAD / HC;

    char* p = (char*)d_ws;
    auto alloc = [&](size_t bytes) { char* r = p; p += pad(bytes); return r; };
    __hip_bfloat16* Wqkv    = (__hip_bfloat16*)alloc((size_t)3 * D_MODEL * C_IN * 2);
    float*          BiasQKV = (float*)alloc((size_t)3 * D_MODEL * 4);
    __hip_bfloat16* Wakv    = (__hip_bfloat16*)alloc((size_t)2 * D_MODEL * C_IN * 2);
    float*          BiasAKV = (float*)alloc((size_t)2 * D_MODEL * 4);
    __hip_bfloat16* Wo      = (__hip_bfloat16*)alloc((size_t)C_IN * D_MODEL * 2);
    __hip_bfloat16* Xt      = (__hip_bfloat16*)alloc((size_t)MS * C_IN * 2);
    __hip_bfloat16* AXt     = (__hip_bfloat16*)alloc((size_t)MA * C_IN * 2);
    __hip_bfloat16* ATT     = (__hip_bfloat16*)alloc((size_t)MS * D_MODEL * 2);
    __hip_bfloat16* qkv_c   = (__hip_bfloat16*)alloc((size_t)3 * DQ * MS * 2);
    __hip_bfloat16* akv_c   = (__hip_bfloat16*)alloc((size_t)2 * DQ * MA * 2);

    prep_weights<<<dim3(3 * D_MODEL * C_IN / 256), 256, 0, stream>>>(
        wq, bq, wk, bk, wv, bv, wo, Wqkv, BiasQKV, Wakv, BiasAKV, Wo, HC);

    transpose_c2m<<<dim3(MS / 32, C_IN / 32), dim3(32, 8), 0, stream>>>(x, Xt, MS);
    transpose_c2m<<<dim3(MA / 32, C_IN / 32), dim3(32, 8), 0, stream>>>(ax, AXt, MA);

    for (int c = 0; c < nchunk; ++c) {
        // qkv_c = Wqkv_chunk[3*DQ,256] * Xt[MS,256]^T (+bias)
        gemm_bt<__hip_bfloat16><<<dim3(MS / 128, 3 * DQ / 128), 256, 0, stream>>>(
            Wqkv + (size_t)c * 3 * DQ * C_IN, Xt, qkv_c,
            BiasQKV + (size_t)c * 3 * DQ, 3 * DQ, MS, C_IN);
        // akv_c = Wakv_chunk[2*DQ,256] * AXt[MA,256]^T (+bias)
        gemm_bt<__hip_bfloat16><<<dim3(MA / 128, 2 * DQ / 128), 256, 0, stream>>>(
            Wakv + (size_t)c * 2 * DQ * C_IN, AXt, akv_c,
            BiasAKV + (size_t)c * 2 * DQ, 2 * DQ, MA, C_IN);
        attn_win<<<dim3(N_SP, HC), 256, 0, stream>>>(qkv_c, akv_c, ATT, DQ, c * HC);
    }

    // out = Wo[256,1024] * ATT[16384,1024]^T (+bo) -> [256,16384] == output layout
    gemm_bt<float><<<dim3(MS / 128, C_IN / 128), 256, 0, stream>>>(
        Wo, ATT, (float*)d_out, bo, C_IN, MS, D_MODEL);
}